// Round 1
// baseline (183.271 us; speedup 1.0000x reference)
//
#include <hip/hip_runtime.h>

typedef __attribute__((ext_vector_type(8))) short bf16x8;
typedef __attribute__((ext_vector_type(4))) float f32x4;

__device__ __forceinline__ unsigned int f2bf(float f) {
  unsigned int u = __builtin_bit_cast(unsigned int, f);
  return (u + 0x7FFFu + ((u >> 16) & 1u)) >> 16;  // RNE to bf16 (no NaN expected)
}
__device__ __forceinline__ float eluf(float x) {
  return x > 0.f ? x : (__expf(x) - 1.f);
}

// ---------------------------------------------------------------------------
// Prep: fold repeat-8 into w1 (-> [256][16], zero-padded K to 32), fold the
// 4-group mean * 0.1 into w5 (-> [16][256] * 0.025), convert all weights to
// bf16 packed in A-fragment order: [mt][kt][lane][8], so a wave's fragment
// load is lane-contiguous 16B (one global_load_dwordx4, fully coalesced).
// ws layout (ushort units):
//   w1p @ 0       : 16 mt * 1 kt * 64 * 8  =   8192
//   w2p @ 8192    : 16 mt * 8 kt * 64 * 8  =  65536
//   w3p @ 73728   :                           65536
//   w4p @ 139264  :                           65536
//   w5p @ 204800  :  1 mt * 8 kt * 64 * 8  =   4096   (total 208896)
// ---------------------------------------------------------------------------
__global__ __launch_bounds__(256) void prep_kernel(
    const float* __restrict__ w1, const float* __restrict__ w2,
    const float* __restrict__ w3, const float* __restrict__ w4,
    const float* __restrict__ w5, unsigned short* __restrict__ ws) {
  int idx = blockIdx.x * 256 + threadIdx.x;  // grid covers exactly 208896
  float v = 0.f;
  if (idx < 8192) {
    int mt = idx >> 9, l = (idx >> 3) & 63, j = idx & 7;
    int o = mt * 16 + (l & 15), c = (l >> 4) * 8 + j;  // c in [0,32)
    if (c < 16) {
      const float* r = w1 + o * 128 + c * 8;
      v = ((r[0] + r[1]) + (r[2] + r[3])) + ((r[4] + r[5]) + (r[6] + r[7]));
    }
  } else if (idx < 204800) {
    int t = idx - 8192;
    int which = t >> 16, e = t & 65535;
    const float* w = (which == 0) ? w2 : (which == 1) ? w3 : w4;
    int mt = e >> 12, kt = (e >> 9) & 7, l = (e >> 3) & 63, j = e & 7;
    int o = mt * 16 + (l & 15), c = kt * 32 + (l >> 4) * 8 + j;
    v = w[o * 256 + c];
  } else {
    int e = idx - 204800;
    int kt = e >> 9, l = (e >> 3) & 63, j = e & 7;
    int d = l & 15, c = kt * 32 + (l >> 4) * 8 + j;
    float s = 0.f;
    if (d < 8) {
      for (int g = 0; g < 4; ++g) s += w5[(g * 8 + d) * 256 + c];
    } else {
      for (int g = 0; g < 4; ++g) s += w5[(32 + g * 8 + (d - 8)) * 256 + c];
    }
    v = 0.025f * s;  // 0.1 * mean over 4 groups
  }
  ws[idx] = (unsigned short)f2bf(v);
}

// ---------------------------------------------------------------------------
// Main: one WG = 64 consecutive pixels of one image row. 4 waves, each wave
// owns 64 out-channels x 64 pixels (4x4 fragments of mfma_f32_16x16x32_bf16).
// Activations ping-pong in two 32KB LDS buffers [64 p][256 k] bf16 with XOR
// swizzle byte ^= ((p&7)<<4) (kills the 512B-row-stride bank conflict).
// MFMA layouts (16x16x32 bf16): A: row=l&15, k=(l>>4)*8+j ; B: col=l&15,
// k=(l>>4)*8+j ; D: col=l&15, row=(l>>4)*4+reg  [per m89-verified mapping].
// ---------------------------------------------------------------------------
__global__ __launch_bounds__(256) void qca_kernel(
    const float* __restrict__ xcat, const unsigned short* __restrict__ wsu,
    float* __restrict__ out) {
  __shared__ __align__(16) char lds[69632];
  char* buf0 = lds;            // 32KB  (also stencil temp, fp32)
  char* buf1 = lds + 32768;    // 32KB
  char* act0 = lds + 65536;    // 4KB:  [64 p][32 k] bf16, swizzle (p&3)<<4
  float* xt = reinterpret_cast<float*>(lds);  // [16 c][3 rr][66 xl]

  const int tid = threadIdx.x;
  const int w = tid >> 6, l = tid & 63;
  const int l15 = l & 15, lhi = l >> 4;

  const int tile = blockIdx.x << 6;  // global pixel base (64 per WG)
  const int bimg = tile >> 16;
  const int y = (tile >> 8) & 255;
  const int x0 = tile & 255;  // in {0,64,128,192}: tile never crosses a row

  // --- stencil halo tile: rows y-1..y+1, cols x0-1..x0+64, all 16 channels
  for (int t = tid; t < 16 * 3 * 66; t += 256) {
    int c = t / 198;
    int rem = t - c * 198;
    int rr = rem / 66;
    int xl = rem - rr * 66;
    int gy = y + rr - 1, gx = x0 + xl - 1;
    float v = 0.f;
    if (gy >= 0 && gy < 256 && gx >= 0 && gx < 256)
      v = xcat[(size_t)(bimg * 16 + c) * 65536 + gy * 256 + gx];
    xt[t] = v;
  }
  __syncthreads();

  // --- neighbor sums -> act0 bf16 (k=16..31 zero-padded for the K=32 MFMA)
  for (int t = tid; t < 2048; t += 256) {
    int p = t & 63, c = t >> 6;  // c in [0,32)
    float v = 0.f;
    if (c < 16) {
      const float* bp = xt + c * 198 + (p + 1);
      v = (bp[-1] + bp[0] + bp[1])          // row y-1
        + (bp[65] + bp[67])                 // row y   (center excluded)
        + (bp[131] + bp[132] + bp[133]);    // row y+1
    }
    reinterpret_cast<unsigned short*>(act0)[p * 32 + (c ^ ((p & 3) << 3))] =
        (unsigned short)f2bf(v);
  }
  __syncthreads();

  f32x4 acc[4][4];

  auto epi = [&](char* dst) {  // ELU + bf16 + swizzled store of this wave's 64x64 tile
#pragma unroll
    for (int mi = 0; mi < 4; ++mi)
#pragma unroll
      for (int ni = 0; ni < 4; ++ni) {
        f32x4 v = acc[mi][ni];
        unsigned int u01 = f2bf(eluf(v[0])) | (f2bf(eluf(v[1])) << 16);
        unsigned int u23 = f2bf(eluf(v[2])) | (f2bf(eluf(v[3])) << 16);
        int o = (w << 6) + mi * 16 + lhi * 4;
        int p = ni * 16 + l15;
        int byte = p * 512 + ((o * 2) ^ ((p & 7) << 4));
        *reinterpret_cast<uint2*>(dst + byte) = uint2{u01, u23};
      }
  };

  // --- layer 1: K=32 (16 real + 16 zero), weights w1p
  {
#pragma unroll
    for (int mi = 0; mi < 4; ++mi)
#pragma unroll
      for (int ni = 0; ni < 4; ++ni) acc[mi][ni] = f32x4{0.f, 0.f, 0.f, 0.f};
    const bf16x8* w1v = reinterpret_cast<const bf16x8*>(wsu);
    bf16x8 a[4], bq[4];
#pragma unroll
    for (int mi = 0; mi < 4; ++mi) a[mi] = w1v[((w << 2) + mi) * 64 + l];
#pragma unroll
    for (int ni = 0; ni < 4; ++ni) {
      int p = ni * 16 + l15;
      bq[ni] = *reinterpret_cast<const bf16x8*>(
          act0 + p * 64 + ((lhi * 16) ^ ((p & 3) << 4)));
    }
#pragma unroll
    for (int mi = 0; mi < 4; ++mi)
#pragma unroll
      for (int ni = 0; ni < 4; ++ni)
        acc[mi][ni] = __builtin_amdgcn_mfma_f32_16x16x32_bf16(
            a[mi], bq[ni], acc[mi][ni], 0, 0, 0);
    epi(buf1);
    __syncthreads();
  }

  // --- middle layers: K=256, 8 k-steps fully unrolled
  auto mid = [&](const char* src, char* dst, const unsigned short* wbase) {
    const bf16x8* wv = reinterpret_cast<const bf16x8*>(wbase);
#pragma unroll
    for (int mi = 0; mi < 4; ++mi)
#pragma unroll
      for (int ni = 0; ni < 4; ++ni) acc[mi][ni] = f32x4{0.f, 0.f, 0.f, 0.f};
#pragma unroll
    for (int kt = 0; kt < 8; ++kt) {
      bf16x8 a[4], bq[4];
#pragma unroll
      for (int mi = 0; mi < 4; ++mi)
        a[mi] = wv[(((w << 2) + mi) * 8 + kt) * 64 + l];
#pragma unroll
      for (int ni = 0; ni < 4; ++ni) {
        int p = ni * 16 + l15;
        int byte = p * 512 + (((kt * 32 + lhi * 8) * 2) ^ ((p & 7) << 4));
        bq[ni] = *reinterpret_cast<const bf16x8*>(src + byte);
      }
#pragma unroll
      for (int mi = 0; mi < 4; ++mi)
#pragma unroll
        for (int ni = 0; ni < 4; ++ni)
          acc[mi][ni] = __builtin_amdgcn_mfma_f32_16x16x32_bf16(
              a[mi], bq[ni], acc[mi][ni], 0, 0, 0);
    }
    epi(dst);
    __syncthreads();
  };

  mid(buf1, buf0, wsu + 8192);    // layer 2
  mid(buf0, buf1, wsu + 73728);   // layer 3
  mid(buf1, buf0, wsu + 139264);  // layer 4

  // --- layer 5: M=16 (folded output), each wave does 16 pixels
  {
    const bf16x8* w5v = reinterpret_cast<const bf16x8*>(wsu + 204800);
    f32x4 a5 = f32x4{0.f, 0.f, 0.f, 0.f};
    const int p = (w << 4) + l15;
#pragma unroll
    for (int kt = 0; kt < 8; ++kt) {
      bf16x8 a = w5v[kt * 64 + l];
      int byte = p * 512 + (((kt * 32 + lhi * 8) * 2) ^ ((p & 7) << 4));
      bf16x8 b = *reinterpret_cast<const bf16x8*>(buf0 + byte);
      a5 = __builtin_amdgcn_mfma_f32_16x16x32_bf16(a, b, a5, 0, 0, 0);
    }
    int pix = tile + p;
    int rem = pix & 65535;
    float* op = out + (size_t)(pix >> 16) * 1048576 + rem;
#pragma unroll
    for (int r = 0; r < 4; ++r) op[(lhi * 4 + r) * 65536] = a5[r];
  }
}

extern "C" void kernel_launch(void* const* d_in, const int* in_sizes, int n_in,
                              void* d_out, int out_size, void* d_ws,
                              size_t ws_size, hipStream_t stream) {
  const float* xcat = (const float*)d_in[0];
  const float* w1 = (const float*)d_in[1];
  const float* w2 = (const float*)d_in[2];
  const float* w3 = (const float*)d_in[3];
  const float* w4 = (const float*)d_in[4];
  const float* w5 = (const float*)d_in[5];
  unsigned short* ws = (unsigned short*)d_ws;  // needs 417,792 bytes
  float* out = (float*)d_out;

  prep_kernel<<<816, 256, 0, stream>>>(w1, w2, w3, w4, w5, ws);
  qca_kernel<<<4096, 256, 0, stream>>>(xcat, ws, out);
}

// Round 2
// 169.021 us; speedup vs baseline: 1.0843x; 1.0843x over previous
//
#include <hip/hip_runtime.h>

typedef __attribute__((ext_vector_type(8))) short bf16x8;
typedef __attribute__((ext_vector_type(4))) float f32x4;

__device__ __forceinline__ unsigned int f2bf(float f) {
  unsigned int u = __builtin_bit_cast(unsigned int, f);
  return (u + 0x7FFFu + ((u >> 16) & 1u)) >> 16;  // RNE to bf16
}
__device__ __forceinline__ float eluf(float x) {
  return x > 0.f ? x : (__expf(x) - 1.f);
}
__device__ __forceinline__ unsigned int cvt_pk_bf16(float a, float b) {
  unsigned int r;
  asm("v_cvt_pk_bf16_f32 %0, %1, %2" : "=v"(r) : "v"(a), "v"(b));
  return r;  // lo = bf16(a), hi = bf16(b), RNE
}

// ---------------------------------------------------------------------------
// Prep (unchanged from R1, verified): fold repeat-8 into w1 (-> [256][16],
// K zero-padded to 32), fold 4-group mean*0.1 into w5 (-> [16][256]*0.025),
// bf16 A-fragment packing [mt][kt][lane][8].
// ws layout (ushort units): w1p@0 (8192), w2p@8192, w3p@73728, w4p@139264
// (65536 each), w5p@204800 (4096).
// ---------------------------------------------------------------------------
__global__ __launch_bounds__(256) void prep_kernel(
    const float* __restrict__ w1, const float* __restrict__ w2,
    const float* __restrict__ w3, const float* __restrict__ w4,
    const float* __restrict__ w5, unsigned short* __restrict__ ws) {
  int idx = blockIdx.x * 256 + threadIdx.x;  // grid covers exactly 208896
  float v = 0.f;
  if (idx < 8192) {
    int mt = idx >> 9, l = (idx >> 3) & 63, j = idx & 7;
    int o = mt * 16 + (l & 15), c = (l >> 4) * 8 + j;  // c in [0,32)
    if (c < 16) {
      const float* r = w1 + o * 128 + c * 8;
      v = ((r[0] + r[1]) + (r[2] + r[3])) + ((r[4] + r[5]) + (r[6] + r[7]));
    }
  } else if (idx < 204800) {
    int t = idx - 8192;
    int which = t >> 16, e = t & 65535;
    const float* w = (which == 0) ? w2 : (which == 1) ? w3 : w4;
    int mt = e >> 12, kt = (e >> 9) & 7, l = (e >> 3) & 63, j = e & 7;
    int o = mt * 16 + (l & 15), c = kt * 32 + (l >> 4) * 8 + j;
    v = w[o * 256 + c];
  } else {
    int e = idx - 204800;
    int kt = e >> 9, l = (e >> 3) & 63, j = e & 7;
    int d = l & 15, c = kt * 32 + (l >> 4) * 8 + j;
    float s = 0.f;
    if (d < 8) {
      for (int g = 0; g < 4; ++g) s += w5[(g * 8 + d) * 256 + c];
    } else {
      for (int g = 0; g < 4; ++g) s += w5[(32 + g * 8 + (d - 8)) * 256 + c];
    }
    v = 0.025f * s;  // 0.1 * mean over 4 groups
  }
  ws[idx] = (unsigned short)f2bf(v);
}

// ---------------------------------------------------------------------------
// Main: one WG = 64 consecutive pixels of one row; 4 waves, each owns
// 64 out-ch x 64 px (4x4 frags of mfma_f32_16x16x32_bf16).
// LDS layout (byte offsets):
//   act0 @ 0     : [64 px][stride 80] bf16, layer-1 input (K=32, 16 zero-pad)
//   buf0 @ 5120  : [64 px][stride 528] bf16 activations
//   buf1 @ 38912 : [64 px][stride 528]
// Stride 528 (512+16) makes bank index 4*((p&7)+lhi) mod 32 -> uniform, no
// conflicts, and addresses are base + compile-time constant (ds offset imm).
// MFMA maps (verified R1): A row=l&15,k=lhi*8+j; B col=l&15,k=lhi*8+j;
// D col=l&15,row=lhi*4+reg.
// ---------------------------------------------------------------------------
#define ACT0 0
#define BUF0 5120
#define BUF1 38912

__global__ __launch_bounds__(256, 2) void qca_kernel(
    const float* __restrict__ xcat, const unsigned short* __restrict__ wsu,
    float* __restrict__ out) {
  __shared__ __align__(16) char lds[72704];
  float* xt = reinterpret_cast<float*>(lds + BUF0);  // [16 c][3 rr][66 xl] fp32

  const int tid = threadIdx.x;
  const int w = tid >> 6, l = tid & 63;
  const int l15 = l & 15, lhi = l >> 4;

  const int tile = blockIdx.x << 6;
  const int bimg = tile >> 16;
  const int y = (tile >> 8) & 255;
  const int x0 = tile & 255;  // {0,64,128,192}: never crosses a row

  // --- stencil halo: rows y-1..y+1, cols x0-1..x0+64, 16 channels
  for (int t = tid; t < 16 * 3 * 66; t += 256) {
    int c = t / 198;
    int rem = t - c * 198;
    int rr = rem / 66;
    int xl = rem - rr * 66;
    int gy = y + rr - 1, gx = x0 + xl - 1;
    float v = 0.f;
    if (gy >= 0 && gy < 256 && gx >= 0 && gx < 256)
      v = xcat[(size_t)(bimg * 16 + c) * 65536 + gy * 256 + gx];
    xt[t] = v;
  }
  __syncthreads();

  // --- neighbor sums -> act0 (k=16..31 zeroed for the K=32 MFMA)
  for (int t = tid; t < 2048; t += 256) {
    int p = t & 63, c = t >> 6;  // c in [0,32)
    float v = 0.f;
    if (c < 16) {
      const float* bp = xt + c * 198 + (p + 1);
      v = (bp[-1] + bp[0] + bp[1]) + (bp[65] + bp[67]) +
          (bp[131] + bp[132] + bp[133]);
    }
    reinterpret_cast<unsigned short*>(lds)[p * 40 + c] = (unsigned short)f2bf(v);
  }
  __syncthreads();

  // per-lane LDS base offsets (all layer/fragment variation goes to ds imm)
  const int lb_r = l15 * 528 + lhi * 16;             // B reads
  const int lb_w = l15 * 528 + w * 128 + lhi * 8;    // epilogue writes
  const int lb_a1 = l15 * 80 + lhi * 16;             // layer-1 act0 reads

  f32x4 acc[4][4];

  auto epi = [&](int dstoff) {  // ELU + pack + store of wave's 64x64 tile
#pragma unroll
    for (int mi = 0; mi < 4; ++mi)
#pragma unroll
      for (int ni = 0; ni < 4; ++ni) {
        f32x4 v = acc[mi][ni];
        unsigned int u01 = cvt_pk_bf16(eluf(v[0]), eluf(v[1]));
        unsigned int u23 = cvt_pk_bf16(eluf(v[2]), eluf(v[3]));
        *reinterpret_cast<uint2*>(lds + lb_w + (dstoff + ni * 8448 + mi * 32)) =
            uint2{u01, u23};
      }
  };

  // --- layer 1: K=32 (16 real + 16 zero)
  {
#pragma unroll
    for (int mi = 0; mi < 4; ++mi)
#pragma unroll
      for (int ni = 0; ni < 4; ++ni) acc[mi][ni] = f32x4{0.f, 0.f, 0.f, 0.f};
    const bf16x8* w1v = reinterpret_cast<const bf16x8*>(wsu);
    bf16x8 a[4], bq[4];
#pragma unroll
    for (int mi = 0; mi < 4; ++mi) a[mi] = w1v[((w << 2) + mi) * 64 + l];
#pragma unroll
    for (int ni = 0; ni < 4; ++ni)
      bq[ni] = *reinterpret_cast<const bf16x8*>(lds + lb_a1 + ni * 1280);
#pragma unroll
    for (int mi = 0; mi < 4; ++mi)
#pragma unroll
      for (int ni = 0; ni < 4; ++ni)
        acc[mi][ni] = __builtin_amdgcn_mfma_f32_16x16x32_bf16(
            a[mi], bq[ni], acc[mi][ni], 0, 0, 0);
    epi(BUF1);
    __syncthreads();
  }

  // --- middle layers: K=256, 8 k-steps unrolled
  auto mid = [&](int srcoff, int dstoff, const unsigned short* wbase) {
    const bf16x8* wv = reinterpret_cast<const bf16x8*>(wbase);
#pragma unroll
    for (int mi = 0; mi < 4; ++mi)
#pragma unroll
      for (int ni = 0; ni < 4; ++ni) acc[mi][ni] = f32x4{0.f, 0.f, 0.f, 0.f};
#pragma unroll
    for (int kt = 0; kt < 8; ++kt) {
      bf16x8 a[4], bq[4];
#pragma unroll
      for (int mi = 0; mi < 4; ++mi)
        a[mi] = wv[(((w << 2) + mi) * 8 + kt) * 64 + l];
#pragma unroll
      for (int ni = 0; ni < 4; ++ni)
        bq[ni] = *reinterpret_cast<const bf16x8*>(
            lds + lb_r + (srcoff + ni * 8448 + kt * 64));
#pragma unroll
      for (int mi = 0; mi < 4; ++mi)
#pragma unroll
        for (int ni = 0; ni < 4; ++ni)
          acc[mi][ni] = __builtin_amdgcn_mfma_f32_16x16x32_bf16(
              a[mi], bq[ni], acc[mi][ni], 0, 0, 0);
    }
    epi(dstoff);
    __syncthreads();
  };

  mid(BUF1, BUF0, wsu + 8192);    // layer 2
  mid(BUF0, BUF1, wsu + 73728);   // layer 3
  mid(BUF1, BUF0, wsu + 139264);  // layer 4

  // --- layer 5: M=16 (folded), each wave handles 16 pixels
  {
    const bf16x8* w5v = reinterpret_cast<const bf16x8*>(wsu + 204800);
    f32x4 a5 = f32x4{0.f, 0.f, 0.f, 0.f};
    const int p = (w << 4) + l15;
    const int lb5 = p * 528 + lhi * 16;
#pragma unroll
    for (int kt = 0; kt < 8; ++kt) {
      bf16x8 a = w5v[kt * 64 + l];
      bf16x8 b = *reinterpret_cast<const bf16x8*>(lds + lb5 + (BUF0 + kt * 64));
      a5 = __builtin_amdgcn_mfma_f32_16x16x32_bf16(a, b, a5, 0, 0, 0);
    }
    int pix = tile + p;
    int rem = pix & 65535;
    float* op = out + (size_t)(pix >> 16) * 1048576 + rem;
#pragma unroll
    for (int r = 0; r < 4; ++r) op[(lhi * 4 + r) * 65536] = a5[r];
  }
}

extern "C" void kernel_launch(void* const* d_in, const int* in_sizes, int n_in,
                              void* d_out, int out_size, void* d_ws,
                              size_t ws_size, hipStream_t stream) {
  const float* xcat = (const float*)d_in[0];
  const float* w1 = (const float*)d_in[1];
  const float* w2 = (const float*)d_in[2];
  const float* w3 = (const float*)d_in[3];
  const float* w4 = (const float*)d_in[4];
  const float* w5 = (const float*)d_in[5];
  unsigned short* ws = (unsigned short*)d_ws;  // 417,792 bytes used
  float* out = (float*)d_out;

  prep_kernel<<<816, 256, 0, stream>>>(w1, w2, w3, w4, w5, ws);
  qca_kernel<<<4096, 256, 0, stream>>>(xcat, ws, out);
}

// Round 3
// 167.761 us; speedup vs baseline: 1.0925x; 1.0075x over previous
//
#include <hip/hip_runtime.h>

typedef __attribute__((ext_vector_type(8))) short bf16x8;
typedef __attribute__((ext_vector_type(4))) float f32x4;

__device__ __forceinline__ unsigned int f2bf(float f) {
  unsigned int u = __builtin_bit_cast(unsigned int, f);
  return (u + 0x7FFFu + ((u >> 16) & 1u)) >> 16;  // RNE to bf16
}
__device__ __forceinline__ float eluf(float x) {
  return x > 0.f ? x : (__expf(x) - 1.f);
}
__device__ __forceinline__ unsigned int cvt_pk_bf16(float a, float b) {
  unsigned int r;
  asm("v_cvt_pk_bf16_f32 %0, %1, %2" : "=v"(r) : "v"(a), "v"(b));
  return r;  // lo = bf16(a), hi = bf16(b), RNE
}

// ---------------------------------------------------------------------------
// Prep (unchanged, verified): fold repeat-8 into w1 (-> [256][16], K padded
// to 32), fold 4-group mean*0.1 into w5 (-> [16][256]*0.025), bf16 A-fragment
// packing [mt][kt][lane][8].
// ws layout (ushort units): w1p@0 (8192), w2p@8192, w3p@73728, w4p@139264
// (65536 each), w5p@204800 (4096).
// ---------------------------------------------------------------------------
__global__ __launch_bounds__(256) void prep_kernel(
    const float* __restrict__ w1, const float* __restrict__ w2,
    const float* __restrict__ w3, const float* __restrict__ w4,
    const float* __restrict__ w5, unsigned short* __restrict__ ws) {
  int idx = blockIdx.x * 256 + threadIdx.x;  // grid covers exactly 208896
  float v = 0.f;
  if (idx < 8192) {
    int mt = idx >> 9, l = (idx >> 3) & 63, j = idx & 7;
    int o = mt * 16 + (l & 15), c = (l >> 4) * 8 + j;  // c in [0,32)
    if (c < 16) {
      const float* r = w1 + o * 128 + c * 8;
      v = ((r[0] + r[1]) + (r[2] + r[3])) + ((r[4] + r[5]) + (r[6] + r[7]));
    }
  } else if (idx < 204800) {
    int t = idx - 8192;
    int which = t >> 16, e = t & 65535;
    const float* w = (which == 0) ? w2 : (which == 1) ? w3 : w4;
    int mt = e >> 12, kt = (e >> 9) & 7, l = (e >> 3) & 63, j = e & 7;
    int o = mt * 16 + (l & 15), c = kt * 32 + (l >> 4) * 8 + j;
    v = w[o * 256 + c];
  } else {
    int e = idx - 204800;
    int kt = e >> 9, l = (e >> 3) & 63, j = e & 7;
    int d = l & 15, c = kt * 32 + (l >> 4) * 8 + j;
    float s = 0.f;
    if (d < 8) {
      for (int g = 0; g < 4; ++g) s += w5[(g * 8 + d) * 256 + c];
    } else {
      for (int g = 0; g < 4; ++g) s += w5[(32 + g * 8 + (d - 8)) * 256 + c];
    }
    v = 0.025f * s;  // 0.1 * mean over 4 groups
  }
  ws[idx] = (unsigned short)f2bf(v);
}

// ---------------------------------------------------------------------------
// Main: one WG = 64 consecutive pixels of one row; 4 waves, each owns
// 64 out-ch x 64 px (4x4 frags of mfma_f32_16x16x32_bf16).
// SINGLE in-place activation buffer (all-waves-read -> barrier -> all-waves-
// write -> barrier) instead of ping-pong: LDS 72.7KB -> 38.9KB => 4 WG/CU.
// LDS layout (byte offsets):
//   buf  @ 0     : [64 px][stride 528] bf16 activations (33792 B)
//   act0 @ 33792 : [64 px][stride 80] bf16 layer-1 input (K=32, 16 zero-pad)
// Stride 528 keeps banks uniform and addresses = per-lane base + ds imm.
// MFMA maps (verified): A row=l&15,k=lhi*8+j; B col=l&15,k=lhi*8+j;
// D col=l&15,row=lhi*4+reg.
// ---------------------------------------------------------------------------
#define ACT0 33792

__global__ __launch_bounds__(256, 4) void qca_kernel(
    const float* __restrict__ xcat, const unsigned short* __restrict__ wsu,
    float* __restrict__ out) {
  __shared__ __align__(16) char lds[38912];
  float* xt = reinterpret_cast<float*>(lds);  // [16 c][3 rr][66 xl] fp32 (aliases buf)

  const int tid = threadIdx.x;
  const int w = tid >> 6, l = tid & 63;
  const int l15 = l & 15, lhi = l >> 4;

  const int tile = blockIdx.x << 6;
  const int bimg = tile >> 16;
  const int y = (tile >> 8) & 255;
  const int x0 = tile & 255;  // {0,64,128,192}: never crosses a row

  // --- stencil halo: rows y-1..y+1, cols x0-1..x0+64, 16 channels
  for (int t = tid; t < 16 * 3 * 66; t += 256) {
    int c = t / 198;
    int rem = t - c * 198;
    int rr = rem / 66;
    int xl = rem - rr * 66;
    int gy = y + rr - 1, gx = x0 + xl - 1;
    float v = 0.f;
    if (gy >= 0 && gy < 256 && gx >= 0 && gx < 256)
      v = xcat[(size_t)(bimg * 16 + c) * 65536 + gy * 256 + gx];
    xt[t] = v;
  }
  __syncthreads();

  // --- neighbor sums -> act0 (k=16..31 zeroed for the K=32 MFMA)
  for (int t = tid; t < 2048; t += 256) {
    int p = t & 63, c = t >> 6;  // c in [0,32)
    float v = 0.f;
    if (c < 16) {
      const float* bp = xt + c * 198 + (p + 1);
      v = (bp[-1] + bp[0] + bp[1]) + (bp[65] + bp[67]) +
          (bp[131] + bp[132] + bp[133]);
    }
    reinterpret_cast<unsigned short*>(lds + ACT0)[p * 40 + c] =
        (unsigned short)f2bf(v);
  }
  __syncthreads();

  // per-lane LDS base offsets (all layer/fragment variation goes to ds imm)
  const int lb_r = l15 * 528 + lhi * 16;           // B reads (buf @ 0)
  const int lb_w = l15 * 528 + w * 128 + lhi * 8;  // epilogue writes
  const int lb_a1 = l15 * 80 + lhi * 16;           // layer-1 act0 reads

  f32x4 acc[4][4];

  auto epi = [&]() {  // ELU + pack + in-place store of wave's 64x64 tile
#pragma unroll
    for (int mi = 0; mi < 4; ++mi)
#pragma unroll
      for (int ni = 0; ni < 4; ++ni) {
        f32x4 v = acc[mi][ni];
        unsigned int u01 = cvt_pk_bf16(eluf(v[0]), eluf(v[1]));
        unsigned int u23 = cvt_pk_bf16(eluf(v[2]), eluf(v[3]));
        *reinterpret_cast<uint2*>(lds + lb_w + (ni * 8448 + mi * 32)) =
            uint2{u01, u23};
      }
  };

  // --- layer 1: K=32 (16 real + 16 zero); reads act0, writes buf (over xt)
  {
#pragma unroll
    for (int mi = 0; mi < 4; ++mi)
#pragma unroll
      for (int ni = 0; ni < 4; ++ni) acc[mi][ni] = f32x4{0.f, 0.f, 0.f, 0.f};
    const bf16x8* w1v = reinterpret_cast<const bf16x8*>(wsu);
    bf16x8 a[4], bq[4];
#pragma unroll
    for (int mi = 0; mi < 4; ++mi) a[mi] = w1v[((w << 2) + mi) * 64 + l];
#pragma unroll
    for (int ni = 0; ni < 4; ++ni)
      bq[ni] = *reinterpret_cast<const bf16x8*>(lds + ACT0 + lb_a1 + ni * 1280);
#pragma unroll
    for (int mi = 0; mi < 4; ++mi)
#pragma unroll
      for (int ni = 0; ni < 4; ++ni)
        acc[mi][ni] = __builtin_amdgcn_mfma_f32_16x16x32_bf16(
            a[mi], bq[ni], acc[mi][ni], 0, 0, 0);
    epi();  // writes buf; other waves only read act0 here -> no race
    __syncthreads();
  }

  // --- middle layers: K=256, 8 k-steps unrolled, in-place update
  auto mid = [&](const unsigned short* wbase) {
    const bf16x8* wv = reinterpret_cast<const bf16x8*>(wbase);
#pragma unroll
    for (int mi = 0; mi < 4; ++mi)
#pragma unroll
      for (int ni = 0; ni < 4; ++ni) acc[mi][ni] = f32x4{0.f, 0.f, 0.f, 0.f};
#pragma unroll
    for (int kt = 0; kt < 8; ++kt) {
      bf16x8 a[4], bq[4];
#pragma unroll
      for (int mi = 0; mi < 4; ++mi)
        a[mi] = wv[(((w << 2) + mi) * 8 + kt) * 64 + l];
#pragma unroll
      for (int ni = 0; ni < 4; ++ni)
        bq[ni] = *reinterpret_cast<const bf16x8*>(
            lds + lb_r + (ni * 8448 + kt * 64));
#pragma unroll
      for (int mi = 0; mi < 4; ++mi)
#pragma unroll
        for (int ni = 0; ni < 4; ++ni)
          acc[mi][ni] = __builtin_amdgcn_mfma_f32_16x16x32_bf16(
              a[mi], bq[ni], acc[mi][ni], 0, 0, 0);
    }
    __syncthreads();  // all waves done reading buf
    epi();            // in-place write
    __syncthreads();  // all writes visible before next layer's reads
  };

  mid(wsu + 8192);    // layer 2
  mid(wsu + 73728);   // layer 3
  mid(wsu + 139264);  // layer 4

  // --- layer 5: M=16 (folded), each wave handles 16 pixels
  {
    const bf16x8* w5v = reinterpret_cast<const bf16x8*>(wsu + 204800);
    f32x4 a5 = f32x4{0.f, 0.f, 0.f, 0.f};
    const int p = (w << 4) + l15;
    const int lb5 = p * 528 + lhi * 16;
#pragma unroll
    for (int kt = 0; kt < 8; ++kt) {
      bf16x8 a = w5v[kt * 64 + l];
      bf16x8 b = *reinterpret_cast<const bf16x8*>(lds + lb5 + kt * 64);
      a5 = __builtin_amdgcn_mfma_f32_16x16x32_bf16(a, b, a5, 0, 0, 0);
    }
    int pix = tile + p;
    int rem = pix & 65535;
    float* op = out + (size_t)(pix >> 16) * 1048576 + rem;
#pragma unroll
    for (int r = 0; r < 4; ++r) op[(lhi * 4 + r) * 65536] = a5[r];
  }
}

extern "C" void kernel_launch(void* const* d_in, const int* in_sizes, int n_in,
                              void* d_out, int out_size, void* d_ws,
                              size_t ws_size, hipStream_t stream) {
  const float* xcat = (const float*)d_in[0];
  const float* w1 = (const float*)d_in[1];
  const float* w2 = (const float*)d_in[2];
  const float* w3 = (const float*)d_in[3];
  const float* w4 = (const float*)d_in[4];
  const float* w5 = (const float*)d_in[5];
  unsigned short* ws = (unsigned short*)d_ws;  // 417,792 bytes used
  float* out = (float*)d_out;

  prep_kernel<<<816, 256, 0, stream>>>(w1, w2, w3, w4, w5, ws);
  qca_kernel<<<4096, 256, 0, stream>>>(xcat, ws, out);
}

// Round 4
// 141.706 us; speedup vs baseline: 1.2933x; 1.1839x over previous
//
#include <hip/hip_runtime.h>

typedef __attribute__((ext_vector_type(8))) short bf16x8;
typedef __attribute__((ext_vector_type(4))) float f32x4;

__device__ __forceinline__ unsigned int f2bf(float f) {
  unsigned int u = __builtin_bit_cast(unsigned int, f);
  return (u + 0x7FFFu + ((u >> 16) & 1u)) >> 16;  // RNE to bf16
}
__device__ __forceinline__ float eluf(float x) {
  return x > 0.f ? x : (__expf(x) - 1.f);
}
__device__ __forceinline__ unsigned int cvt_pk_bf16(float a, float b) {
  unsigned int r;
  asm("v_cvt_pk_bf16_f32 %0, %1, %2" : "=v"(r) : "v"(a), "v"(b));
  return r;  // lo = bf16(a), hi = bf16(b), RNE
}

// ---------------------------------------------------------------------------
// Prep (unchanged, verified): fold repeat-8 into w1 (-> [256][16], K padded
// to 32), fold 4-group mean*0.1 into w5 (-> [16][256]*0.025), bf16 A-fragment
// packing [mt][kt][lane][8].
// ws layout (ushort units): w1p@0 (8192), w2p@8192, w3p@73728, w4p@139264
// (65536 each), w5p@204800 (4096).
// ---------------------------------------------------------------------------
__global__ __launch_bounds__(256) void prep_kernel(
    const float* __restrict__ w1, const float* __restrict__ w2,
    const float* __restrict__ w3, const float* __restrict__ w4,
    const float* __restrict__ w5, unsigned short* __restrict__ ws) {
  int idx = blockIdx.x * 256 + threadIdx.x;  // grid covers exactly 208896
  float v = 0.f;
  if (idx < 8192) {
    int mt = idx >> 9, l = (idx >> 3) & 63, j = idx & 7;
    int o = mt * 16 + (l & 15), c = (l >> 4) * 8 + j;  // c in [0,32)
    if (c < 16) {
      const float* r = w1 + o * 128 + c * 8;
      v = ((r[0] + r[1]) + (r[2] + r[3])) + ((r[4] + r[5]) + (r[6] + r[7]));
    }
  } else if (idx < 204800) {
    int t = idx - 8192;
    int which = t >> 16, e = t & 65535;
    const float* w = (which == 0) ? w2 : (which == 1) ? w3 : w4;
    int mt = e >> 12, kt = (e >> 9) & 7, l = (e >> 3) & 63, j = e & 7;
    int o = mt * 16 + (l & 15), c = kt * 32 + (l >> 4) * 8 + j;
    v = w[o * 256 + c];
  } else {
    int e = idx - 204800;
    int kt = e >> 9, l = (e >> 3) & 63, j = e & 7;
    int d = l & 15, c = kt * 32 + (l >> 4) * 8 + j;
    float s = 0.f;
    if (d < 8) {
      for (int g = 0; g < 4; ++g) s += w5[(g * 8 + d) * 256 + c];
    } else {
      for (int g = 0; g < 4; ++g) s += w5[(32 + g * 8 + (d - 8)) * 256 + c];
    }
    v = 0.025f * s;  // 0.1 * mean over 4 groups
  }
  ws[idx] = (unsigned short)f2bf(v);
}

// ---------------------------------------------------------------------------
// Main: one WG = 64 consecutive pixels of one row; 4 waves, each owns
// 64 out-ch x 64 px (4x4 frags of mfma_f32_16x16x32_bf16).
// Single in-place activation buffer (read -> barrier -> write -> barrier).
// LDS layout (byte offsets):
//   buf  @ 0     : [64 px][stride 528] bf16 activations (33792 B)
//   act0 @ 33792 : [64 px][stride 80] bf16 layer-1 input (K=32, 16 zero-pad)
// Stride 528 keeps banks uniform; addresses = per-lane base + ds imm.
// MFMA maps (verified): A row=l&15,k=lhi*8+j; B col=l&15,k=lhi*8+j;
// D col=l&15,row=lhi*4+reg.
// launch_bounds(256,3): reg demand ~156/wave (64 AGPR acc + ~92 arch); the
// (256,4)=128-cap forced spills (R3: +100MB HBM scratch traffic). 3 waves/
// SIMD is the largest spill-free occupancy.
// ---------------------------------------------------------------------------
#define ACT0 33792

__global__ __launch_bounds__(256, 3) void qca_kernel(
    const float* __restrict__ xcat, const unsigned short* __restrict__ wsu,
    float* __restrict__ out) {
  __shared__ __align__(16) char lds[38912];
  float* xt = reinterpret_cast<float*>(lds);  // [16 c][3 rr][66 xl] fp32 (aliases buf)

  const int tid = threadIdx.x;
  const int w = tid >> 6, l = tid & 63;
  const int l15 = l & 15, lhi = l >> 4;

  const int tile = blockIdx.x << 6;
  const int bimg = tile >> 16;
  const int y = (tile >> 8) & 255;
  const int x0 = tile & 255;  // {0,64,128,192}: never crosses a row

  // --- stencil halo: rows y-1..y+1, cols x0-1..x0+64, 16 channels
  for (int t = tid; t < 16 * 3 * 66; t += 256) {
    int c = t / 198;
    int rem = t - c * 198;
    int rr = rem / 66;
    int xl = rem - rr * 66;
    int gy = y + rr - 1, gx = x0 + xl - 1;
    float v = 0.f;
    if (gy >= 0 && gy < 256 && gx >= 0 && gx < 256)
      v = xcat[(size_t)(bimg * 16 + c) * 65536 + gy * 256 + gx];
    xt[t] = v;
  }
  __syncthreads();

  // --- neighbor sums -> act0 (k=16..31 zeroed for the K=32 MFMA)
  for (int t = tid; t < 2048; t += 256) {
    int p = t & 63, c = t >> 6;  // c in [0,32)
    float v = 0.f;
    if (c < 16) {
      const float* bp = xt + c * 198 + (p + 1);
      v = (bp[-1] + bp[0] + bp[1]) + (bp[65] + bp[67]) +
          (bp[131] + bp[132] + bp[133]);
    }
    reinterpret_cast<unsigned short*>(lds + ACT0)[p * 40 + c] =
        (unsigned short)f2bf(v);
  }
  __syncthreads();

  // per-lane LDS base offsets (all layer/fragment variation goes to ds imm)
  const int lb_r = l15 * 528 + lhi * 16;           // B reads (buf @ 0)
  const int lb_w = l15 * 528 + w * 128 + lhi * 8;  // epilogue writes
  const int lb_a1 = l15 * 80 + lhi * 16;           // layer-1 act0 reads

  f32x4 acc[4][4];

  auto epi = [&]() {  // ELU + pack + in-place store of wave's 64x64 tile
#pragma unroll
    for (int mi = 0; mi < 4; ++mi)
#pragma unroll
      for (int ni = 0; ni < 4; ++ni) {
        f32x4 v = acc[mi][ni];
        unsigned int u01 = cvt_pk_bf16(eluf(v[0]), eluf(v[1]));
        unsigned int u23 = cvt_pk_bf16(eluf(v[2]), eluf(v[3]));
        *reinterpret_cast<uint2*>(lds + lb_w + (ni * 8448 + mi * 32)) =
            uint2{u01, u23};
      }
  };

  // --- layer 1: K=32 (16 real + 16 zero); reads act0, writes buf (over xt)
  {
#pragma unroll
    for (int mi = 0; mi < 4; ++mi)
#pragma unroll
      for (int ni = 0; ni < 4; ++ni) acc[mi][ni] = f32x4{0.f, 0.f, 0.f, 0.f};
    const bf16x8* w1v = reinterpret_cast<const bf16x8*>(wsu);
    bf16x8 bq[4];
#pragma unroll
    for (int ni = 0; ni < 4; ++ni)
      bq[ni] = *reinterpret_cast<const bf16x8*>(lds + ACT0 + lb_a1 + ni * 1280);
#pragma unroll
    for (int mi = 0; mi < 4; ++mi) {
      bf16x8 a = w1v[((w << 2) + mi) * 64 + l];
#pragma unroll
      for (int ni = 0; ni < 4; ++ni)
        acc[mi][ni] = __builtin_amdgcn_mfma_f32_16x16x32_bf16(
            a, bq[ni], acc[mi][ni], 0, 0, 0);
    }
    epi();  // writes buf; other waves only read act0 here -> no race
    __syncthreads();
  }

  // --- middle layers: K=256, 8 k-steps unrolled, in-place update.
  // bq loaded once per kt; per-mi A-fragment loaded just-in-time to keep
  // live operand regs ~24 (pressure: fit under the 3-wave/SIMD budget).
  auto mid = [&](const unsigned short* wbase) {
    const bf16x8* wv = reinterpret_cast<const bf16x8*>(wbase);
#pragma unroll
    for (int mi = 0; mi < 4; ++mi)
#pragma unroll
      for (int ni = 0; ni < 4; ++ni) acc[mi][ni] = f32x4{0.f, 0.f, 0.f, 0.f};
#pragma unroll
    for (int kt = 0; kt < 8; ++kt) {
      bf16x8 bq[4];
#pragma unroll
      for (int ni = 0; ni < 4; ++ni)
        bq[ni] = *reinterpret_cast<const bf16x8*>(
            lds + lb_r + (ni * 8448 + kt * 64));
#pragma unroll
      for (int mi = 0; mi < 4; ++mi) {
        bf16x8 a = wv[(((w << 2) + mi) * 8 + kt) * 64 + l];
#pragma unroll
        for (int ni = 0; ni < 4; ++ni)
          acc[mi][ni] = __builtin_amdgcn_mfma_f32_16x16x32_bf16(
              a, bq[ni], acc[mi][ni], 0, 0, 0);
      }
    }
    __syncthreads();  // all waves done reading buf
    epi();            // in-place write
    __syncthreads();  // all writes visible before next layer's reads
  };

  mid(wsu + 8192);    // layer 2
  mid(wsu + 73728);   // layer 3
  mid(wsu + 139264);  // layer 4

  // --- layer 5: M=16 (folded), each wave handles 16 pixels
  {
    const bf16x8* w5v = reinterpret_cast<const bf16x8*>(wsu + 204800);
    f32x4 a5 = f32x4{0.f, 0.f, 0.f, 0.f};
    const int p = (w << 4) + l15;
    const int lb5 = p * 528 + lhi * 16;
#pragma unroll
    for (int kt = 0; kt < 8; ++kt) {
      bf16x8 a = w5v[kt * 64 + l];
      bf16x8 b = *reinterpret_cast<const bf16x8*>(lds + lb5 + kt * 64);
      a5 = __builtin_amdgcn_mfma_f32_16x16x32_bf16(a, b, a5, 0, 0, 0);
    }
    int pix = tile + p;
    int rem = pix & 65535;
    float* op = out + (size_t)(pix >> 16) * 1048576 + rem;
#pragma unroll
    for (int r = 0; r < 4; ++r) op[(lhi * 4 + r) * 65536] = a5[r];
  }
}

extern "C" void kernel_launch(void* const* d_in, const int* in_sizes, int n_in,
                              void* d_out, int out_size, void* d_ws,
                              size_t ws_size, hipStream_t stream) {
  const float* xcat = (const float*)d_in[0];
  const float* w1 = (const float*)d_in[1];
  const float* w2 = (const float*)d_in[2];
  const float* w3 = (const float*)d_in[3];
  const float* w4 = (const float*)d_in[4];
  const float* w5 = (const float*)d_in[5];
  unsigned short* ws = (unsigned short*)d_ws;  // 417,792 bytes used
  float* out = (float*)d_out;

  prep_kernel<<<816, 256, 0, stream>>>(w1, w2, w3, w4, w5, ws);
  qca_kernel<<<4096, 256, 0, stream>>>(xcat, ws, out);
}